// Round 1
// baseline (224.874 us; speedup 1.0000x reference)
//
#include <hip/hip_runtime.h>
#include <hip/hip_bf16.h>
#include <stdint.h>

typedef __attribute__((ext_vector_type(8))) short short8;
typedef __attribute__((ext_vector_type(4))) float f32x4;
typedef __attribute__((ext_vector_type(4))) unsigned short ushort4v;

#define TT 2048
#define HH 16
#define CCdim 1024
#define BT 4096   // B*T

// round-to-nearest-even f32 -> bf16 (matches jnp astype)
__device__ inline unsigned short f2bf(float f) {
  unsigned u = __float_as_uint(f);
  u += 0x7FFF + ((u >> 16) & 1);
  return (unsigned short)(u >> 16);
}
__device__ inline float bf2f(unsigned short s) {
  return __uint_as_float(((unsigned)s) << 16);
}

__device__ inline void gload16(const unsigned short* g, unsigned short* l) {
  __builtin_amdgcn_global_load_lds((const __attribute__((address_space(1))) void*)g,
                                   (__attribute__((address_space(3))) void*)l, 16, 0, 0);
}

// ---------------- prep: casts + bf16-rounded rope table ----------------
__global__ __launch_bounds__(256) void prep(const float* __restrict__ x, const float* __restrict__ wq,
                     const float* __restrict__ wk, const float* __restrict__ wv,
                     const float* __restrict__ wp, unsigned short* __restrict__ xb,
                     unsigned short* __restrict__ wqkv, unsigned short* __restrict__ wpb,
                     float2* __restrict__ tab) {
  long idx = (long)blockIdx.x * blockDim.x + threadIdx.x;
  const long NX = (long)BT * CCdim;        // 4194304
  const long NW = (long)CCdim * CCdim;     // 1048576
  if (idx < NX) { xb[idx] = f2bf(x[idx]); return; }
  idx -= NX;
  if (idx < NW) { wqkv[idx] = f2bf(wq[idx]); return; }
  idx -= NW;
  if (idx < NW) { wqkv[NW + idx] = f2bf(wk[idx]); return; }
  idx -= NW;
  if (idx < NW) { wqkv[2 * NW + idx] = f2bf(wv[idx]); return; }
  idx -= NW;
  if (idx < NW) { wpb[idx] = f2bf(wp[idx]); return; }
  idx -= NW;
  if (idx < (long)TT * 32) {
    int t = (int)(idx >> 5), i = (int)(idx & 31);
    float invf = powf(10000.0f, -(float)i / 32.0f);
    float a = (float)t * invf;
    tab[idx] = make_float2(bf2f(f2bf(cosf(a))), bf2f(f2bf(sinf(a))));
  }
}

// ---------------- GEMM: C[m][n] = sum_k A[m][k] * W[n][k]  (both row-major, K=1024) ----
// 128x128 tile, BK=32, 4 waves (2x2), 16x16x32 bf16 MFMA, global_load_lds + XOR swizzle.
// LDS layout: [128 rows][32 bf16]; 16B chunk c of row r stored at slot c ^ ((r>>1)&3).
__global__ __launch_bounds__(256) void gemm_bt(const unsigned short* __restrict__ A,
                                               const unsigned short* __restrict__ W,
                                               float* __restrict__ C, int ldc) {
  __shared__ __align__(16) unsigned short As[128 * 32];
  __shared__ __align__(16) unsigned short Ws[128 * 32];
  const int K = 1024;
  const int tid = threadIdx.x;
  const int lane = tid & 63;
  const int wid = tid >> 6;
  const int wr = wid >> 1, wc = wid & 1;
  const int m0 = blockIdx.y * 128;
  const int n0 = blockIdx.x * 128;

  f32x4 acc[4][4] = {};

  // staging: issue i covers rows (i*256+tid)/4, chunk tid&3 (8 bf16 = 16B)
  const int srow0 = tid >> 2;
  const int cgrp = tid & 3;
  const int cd = (cgrp ^ ((srow0 >> 1) & 3)) * 8;   // same for issue1 (row+64 keeps (r>>1)&3)
  const unsigned short* Arow0 = A + (long)(m0 + srow0) * K + cd;
  const unsigned short* Arow1 = A + (long)(m0 + srow0 + 64) * K + cd;
  const unsigned short* Wrow0 = W + (long)(n0 + srow0) * K + cd;
  const unsigned short* Wrow1 = W + (long)(n0 + srow0 + 64) * K + cd;
  unsigned short* ldsA0 = As + wid * 512;
  unsigned short* ldsA1 = As + 2048 + wid * 512;
  unsigned short* ldsW0 = Ws + wid * 512;
  unsigned short* ldsW1 = Ws + 2048 + wid * 512;

  for (int kt = 0; kt < 32; ++kt) {
    const int kof = kt * 32;
    gload16(Arow0 + kof, ldsA0);
    gload16(Arow1 + kof, ldsA1);
    gload16(Wrow0 + kof, ldsW0);
    gload16(Wrow1 + kof, ldsW1);
    asm volatile("s_waitcnt vmcnt(0)" ::: "memory");
    __syncthreads();
    short8 af[4], bf[4];
#pragma unroll
    for (int mi = 0; mi < 4; ++mi) {
      int r = wr * 64 + mi * 16 + (lane & 15);
      af[mi] = *(const short8*)&As[r * 32 + (((lane >> 4) ^ ((r >> 1) & 3)) * 8)];
    }
#pragma unroll
    for (int nj = 0; nj < 4; ++nj) {
      int r = wc * 64 + nj * 16 + (lane & 15);
      bf[nj] = *(const short8*)&Ws[r * 32 + (((lane >> 4) ^ ((r >> 1) & 3)) * 8)];
    }
#pragma unroll
    for (int mi = 0; mi < 4; ++mi)
#pragma unroll
      for (int nj = 0; nj < 4; ++nj)
        acc[mi][nj] = __builtin_amdgcn_mfma_f32_16x16x32_bf16(af[mi], bf[nj], acc[mi][nj], 0, 0, 0);
    __syncthreads();
  }
#pragma unroll
  for (int mi = 0; mi < 4; ++mi)
#pragma unroll
    for (int nj = 0; nj < 4; ++nj)
#pragma unroll
      for (int j = 0; j < 4; ++j) {
        int rr = m0 + wr * 64 + mi * 16 + 4 * (lane >> 4) + j;
        int ncol = n0 + wc * 64 + nj * 16 + (lane & 15);
        C[(long)rr * ldc + ncol] = acc[mi][nj][j];
      }
}

// ---------------- RMSNorm + RoPE on q,k; write (B,H,T,hd) bf16; fold 1/8 scale into Q ----
__global__ __launch_bounds__(256) void rmsrope(const float* __restrict__ qkv, const float* __restrict__ g,
                                               const float2* __restrict__ tab,
                                               unsigned short* __restrict__ Qh,
                                               unsigned short* __restrict__ Kh) {
  int rid = blockIdx.x * 4 + (threadIdx.x >> 6);  // (b*T + t)*H + h
  int lane = threadIdx.x & 63;
  int h = rid & 15;
  int bt = rid >> 4;
  int t = bt & (TT - 1);
  int b = bt >> 11;
  const float* src = qkv + (long)bt * 3072;
  float2 cs = tab[t * 32 + (lane & 31)];
  float gg = g[lane];
  float sgn = (lane < 32) ? 1.0f : -1.0f;
  long dst = (((long)(b * 16 + h) * TT + t)) * 64 + lane;
#pragma unroll
  for (int qk = 0; qk < 2; ++qk) {
    float u = src[qk * 1024 + h * 64 + lane];
    float ss = u * u;
    ss += __shfl_xor(ss, 1);  ss += __shfl_xor(ss, 2);  ss += __shfl_xor(ss, 4);
    ss += __shfl_xor(ss, 8);  ss += __shfl_xor(ss, 16); ss += __shfl_xor(ss, 32);
    float r = rsqrtf(ss * (1.0f / 64.0f) + 1e-5f);
    float xn = u * r * gg;
    float pr = __shfl_xor(xn, 32);
    float out = xn * cs.x + sgn * pr * cs.y;
    if (qk == 0) Qh[dst] = f2bf(out * 0.125f);  // fold 1/sqrt(64): exact pow2, no extra rounding
    else         Kh[dst] = f2bf(out);
  }
}

// ---------------- V repack: qkv f32 (cols 2048..3071) -> Vt bf16 (B,H,hd,T) ----------
__global__ __launch_bounds__(256) void vrepack(const float* __restrict__ qkv,
                                               unsigned short* __restrict__ Vt) {
  __shared__ __align__(16) unsigned short S[64][72];
  int blk = blockIdx.x;          // bh*32 + ttile
  int bh = blk >> 5;
  int tt = blk & 31;
  int b = bh >> 4, h = bh & 15;
  int tid = threadIdx.x;
#pragma unroll
  for (int pass = 0; pass < 4; ++pass) {
    int tl = pass * 16 + (tid >> 4);
    int cg = tid & 15;
    float4 v = *(const float4*)&qkv[(long)(b * TT + tt * 64 + tl) * 3072 + 2048 + h * 64 + cg * 4];
    ushort4v o = { f2bf(v.x), f2bf(v.y), f2bf(v.z), f2bf(v.w) };
    *(ushort4v*)&S[tl][cg * 4] = o;
  }
  __syncthreads();
  int d = tid >> 2, ts = tid & 3;
  short8 o0, o1;
#pragma unroll
  for (int t2 = 0; t2 < 8; ++t2) o0[t2] = (short)S[ts * 16 + t2][d];
#pragma unroll
  for (int t2 = 0; t2 < 8; ++t2) o1[t2] = (short)S[ts * 16 + 8 + t2][d];
  unsigned short* dst = Vt + ((long)bh * 64 + d) * TT + tt * 64 + ts * 16;
  *(short8*)dst = o0;
  *(short8*)(dst + 8) = o1;
}

// ---------------- flash attention (no mask), 8 waves x 16 q-rows, KV tile 64 --------
__global__ __launch_bounds__(512) void attn(const unsigned short* __restrict__ Qh,
                                            const unsigned short* __restrict__ Kh,
                                            const unsigned short* __restrict__ Vt,
                                            unsigned short* __restrict__ Y) {
  __shared__ __align__(16) unsigned short Kl[64 * 72];
  __shared__ __align__(16) unsigned short Vl[64 * 72];
  __shared__ __align__(16) unsigned short Pl[8][16 * 72];
  const int tid = threadIdx.x;
  const int lane = tid & 63;
  const int wid = tid >> 6;
  const int qt = blockIdx.x & 15;
  const int bh = blockIdx.x >> 4;
  const int b = bh >> 4, h = bh & 15;
  const long bhT = (long)bh * TT;
  const int q0 = qt * 128 + wid * 16;
  const f32x4 zero = {0.f, 0.f, 0.f, 0.f};

  short8 qf[2];
#pragma unroll
  for (int c = 0; c < 2; ++c)
    qf[c] = *(const short8*)(Qh + (bhT + q0 + (lane & 15)) * 64 + c * 32 + 8 * (lane >> 4));

  float m[4], ell[4];
  f32x4 oacc[4] = {};
#pragma unroll
  for (int j = 0; j < 4; ++j) { m[j] = -1e30f; ell[j] = 0.f; }

  const int srow = tid >> 3, scw = tid & 7;
  const unsigned short* Ksrc = Kh + (bhT + srow) * 64 + scw * 8;
  const unsigned short* Vsrc = Vt + ((long)bh * 64 + srow) * TT + scw * 8;
  unsigned short* Kdst = &Kl[srow * 72 + scw * 8];
  unsigned short* Vdst = &Vl[srow * 72 + scw * 8];
  unsigned short* pw = &Pl[wid][0];

  for (int kt = 0; kt < 32; ++kt) {
    __syncthreads();
    *(short8*)Kdst = *(const short8*)(Ksrc + (long)kt * 64 * 64);
    *(short8*)Vdst = *(const short8*)(Vsrc + kt * 64);
    __syncthreads();
    // scores: s[ct] = (Q/8) . K^T for 16 cols at a time
    f32x4 s[4];
#pragma unroll
    for (int ct = 0; ct < 4; ++ct) {
      short8 k0 = *(const short8*)&Kl[(ct * 16 + (lane & 15)) * 72 + 8 * (lane >> 4)];
      short8 k1 = *(const short8*)&Kl[(ct * 16 + (lane & 15)) * 72 + 32 + 8 * (lane >> 4)];
      s[ct] = __builtin_amdgcn_mfma_f32_16x16x32_bf16(qf[0], k0, zero, 0, 0, 0);
      s[ct] = __builtin_amdgcn_mfma_f32_16x16x32_bf16(qf[1], k1, s[ct], 0, 0, 0);
    }
    // online softmax (rows = 4*(lane>>4)+j, cols spread over 16-lane group)
    float tm[4];
#pragma unroll
    for (int j = 0; j < 4; ++j)
      tm[j] = fmaxf(fmaxf(s[0][j], s[1][j]), fmaxf(s[2][j], s[3][j]));
#pragma unroll
    for (int j = 0; j < 4; ++j) {
      tm[j] = fmaxf(tm[j], __shfl_xor(tm[j], 1));
      tm[j] = fmaxf(tm[j], __shfl_xor(tm[j], 2));
      tm[j] = fmaxf(tm[j], __shfl_xor(tm[j], 4));
      tm[j] = fmaxf(tm[j], __shfl_xor(tm[j], 8));
    }
    float corr[4], rs[4];
#pragma unroll
    for (int j = 0; j < 4; ++j) {
      float mn = fmaxf(m[j], tm[j]);
      corr[j] = __expf(m[j] - mn);
      m[j] = mn;
      rs[j] = 0.f;
    }
#pragma unroll
    for (int ct = 0; ct < 4; ++ct)
#pragma unroll
      for (int j = 0; j < 4; ++j) {
        float p = __expf(s[ct][j] - m[j]);
        s[ct][j] = p;
        rs[j] += p;
      }
#pragma unroll
    for (int j = 0; j < 4; ++j) {
      rs[j] += __shfl_xor(rs[j], 1);
      rs[j] += __shfl_xor(rs[j], 2);
      rs[j] += __shfl_xor(rs[j], 4);
      rs[j] += __shfl_xor(rs[j], 8);
      ell[j] = ell[j] * corr[j] + rs[j];
    }
#pragma unroll
    for (int dct = 0; dct < 4; ++dct) {
      oacc[dct][0] *= corr[0]; oacc[dct][1] *= corr[1];
      oacc[dct][2] *= corr[2]; oacc[dct][3] *= corr[3];
    }
    // P -> LDS (D-layout), reread as A-frags
#pragma unroll
    for (int ct = 0; ct < 4; ++ct)
#pragma unroll
      for (int j = 0; j < 4; ++j)
        pw[(4 * (lane >> 4) + j) * 72 + ct * 16 + (lane & 15)] = f2bf(s[ct][j]);
    asm volatile("s_waitcnt lgkmcnt(0)" ::: "memory");
    short8 pf0 = *(const short8*)&pw[(lane & 15) * 72 + 8 * (lane >> 4)];
    short8 pf1 = *(const short8*)&pw[(lane & 15) * 72 + 32 + 8 * (lane >> 4)];
#pragma unroll
    for (int dct = 0; dct < 4; ++dct) {
      short8 v0 = *(const short8*)&Vl[(dct * 16 + (lane & 15)) * 72 + 8 * (lane >> 4)];
      short8 v1 = *(const short8*)&Vl[(dct * 16 + (lane & 15)) * 72 + 32 + 8 * (lane >> 4)];
      oacc[dct] = __builtin_amdgcn_mfma_f32_16x16x32_bf16(pf0, v0, oacc[dct], 0, 0, 0);
      oacc[dct] = __builtin_amdgcn_mfma_f32_16x16x32_bf16(pf1, v1, oacc[dct], 0, 0, 0);
    }
  }
#pragma unroll
  for (int dct = 0; dct < 4; ++dct)
#pragma unroll
    for (int j = 0; j < 4; ++j) {
      int row = q0 + 4 * (lane >> 4) + j;
      float val = oacc[dct][j] / ell[j];
      Y[((long)b * TT + row) * CCdim + h * 64 + dct * 16 + (lane & 15)] = f2bf(val);
    }
}

extern "C" void kernel_launch(void* const* d_in, const int* in_sizes, int n_in,
                              void* d_out, int out_size, void* d_ws, size_t ws_size,
                              hipStream_t stream) {
  const float* x  = (const float*)d_in[0];
  const float* wq = (const float*)d_in[1];
  const float* wk = (const float*)d_in[2];
  const float* wv = (const float*)d_in[3];
  const float* wp = (const float*)d_in[4];
  const float* g  = (const float*)d_in[5];

  char* w = (char*)d_ws;
  unsigned short* xb   = (unsigned short*)w; w += (long)BT * CCdim * 2;       // 8 MB
  unsigned short* wqkv = (unsigned short*)w; w += (long)3 * CCdim * CCdim * 2; // 6 MB
  unsigned short* wpb  = (unsigned short*)w; w += (long)CCdim * CCdim * 2;    // 2 MB
  float* qkv           = (float*)w;          w += (long)BT * 3 * CCdim * 4;   // 48 MB
  unsigned short* qh   = (unsigned short*)w; w += (long)BT * CCdim * 2;
  unsigned short* kh   = (unsigned short*)w; w += (long)BT * CCdim * 2;
  unsigned short* vt   = (unsigned short*)w; w += (long)BT * CCdim * 2;
  unsigned short* yb   = (unsigned short*)w; w += (long)BT * CCdim * 2;
  float2* tab          = (float2*)w;         w += (long)TT * 32 * 8;

  long total = (long)BT * CCdim + 4L * CCdim * CCdim + (long)TT * 32;
  int pblocks = (int)((total + 255) / 256);
  prep<<<pblocks, 256, 0, stream>>>(x, wq, wk, wv, wp, xb, wqkv, wpb, tab);
  gemm_bt<<<dim3(24, 32), 256, 0, stream>>>(xb, wqkv, qkv, 3072);
  rmsrope<<<16384, 256, 0, stream>>>(qkv, g, tab, qh, kh);
  vrepack<<<1024, 256, 0, stream>>>(qkv, vt);
  attn<<<512, 512, 0, stream>>>(qh, kh, vt, yb);
  gemm_bt<<<dim3(8, 32), 256, 0, stream>>>(yb, wpb, (float*)d_out, 1024);
}